// Round 13
// baseline (130.331 us; speedup 1.0000x reference)
//
#include <hip/hip_runtime.h>
#include <stdint.h>

#define BB 8
#define NN 2048
#define CC 64
#define KK 32
#define DK 16
#define RADIUSF 0.2f
#define EPSF 1e-8f
#define BN_EPSF 1e-5f

typedef unsigned long long u64;
typedef unsigned int u32;

// --- fp32 helpers matching the reference's arithmetic ---
__device__ __forceinline__ float refsq3(float a, float b, float c) {
  return __fadd_rn(__fadd_rn(__fmul_rn(a, a), __fmul_rn(b, b)), __fmul_rn(c, c));
}
__device__ __forceinline__ float refdot3(float ax, float ay, float az,
                                         float bx, float by, float bz) {
  return __builtin_fmaf(az, bz, __builtin_fmaf(ay, by, __fmul_rn(ax, bx)));
}
__device__ __forceinline__ float refdist(float sx, float sy, float dt) {
  float d2 = __fsub_rn(__fadd_rn(sx, sy), __fmul_rn(2.0f, dt));
  d2 = fmaxf(d2, 0.0f);
  return d2 > 0.0f ? __fsqrt_rn(d2) : 0.0f;
}

// cross-lane bitonic sort of one u32 per lane, ascending by lane index
#define WAVE_SORT64(V)                                                        \
  {                                                                           \
    _Pragma("unroll") for (int k_ = 2; k_ <= 64; k_ <<= 1) {                  \
      _Pragma("unroll") for (int j_ = k_ >> 1; j_ >= 1; j_ >>= 1) {           \
        u32 o_ = __shfl_xor(V, j_);                                           \
        bool keepmin_ = ((lane & k_) == 0) == ((lane & j_) == 0);             \
        u32 mn_ = V < o_ ? V : o_;                                            \
        u32 mx_ = V < o_ ? o_ : V;                                            \
        V = keepmin_ ? mn_ : mx_;                                             \
      }                                                                       \
    }                                                                         \
  }

// ---------------------------------------------------------------------------
// Kernel 0: pack coords + exact ref-rounded sq-norm into float4 (x,y,z,sn).
// ---------------------------------------------------------------------------
__global__ __launch_bounds__(256) void pack_kernel(const float* __restrict__ coords,
                                                   float4* __restrict__ P) {
  int t = blockIdx.x * 256 + threadIdx.x;   // 0..16383
  float x = coords[t * 3 + 0], y = coords[t * 3 + 1], z = coords[t * 3 + 2];
  P[t] = make_float4(x, y, z, refsq3(x, y, z));
}

// ---------------------------------------------------------------------------
// Mega kernel: knn (even blocks) CONCURRENT WITH gfeat (odd blocks).
// Rationale (r12 post-mortem): gfeat is independent of knn but the stream
// serializes kernels (no events/multi-stream under graph capture). Role-split
// blocks co-schedule both on every CU: gfeat's dense FMA waves fill knn's
// latency stalls (knn VALUBusy 64%). Both bodies byte-identical to r12.
// P was relocated out of G's region (knn reads P while gfeat writes G).
//
// knn role: exact KNN-SET, threshold prefilter + survivor select, 1 wave/query.
//   T = A[31] of sorted lane-minima. THEOREM: #{values < D} <= 31 => at most
//   31 lane-minima < D => A[31] >= D. Survivors n = #{du<=T} ~40-50; n<=64:
//   ballot-compact values to LDS strip, sort-64 -> D = S[31]; else exact
//   bit-descent fallback. Emit: du<D via scan; ties via ballot rank (j asc).
// gfeat role: G[b][n][c] = inv[c]*(W_f[c,:]·feats[b,:,n]) + shift[c],
//   conv_w staged in LDS padded [64][65].
// ---------------------------------------------------------------------------
__global__ __launch_bounds__(256) void mega_kernel(
    const float4* __restrict__ P, int* __restrict__ idx_out,
    const float* __restrict__ feats, const float* __restrict__ conv_w,
    const float* __restrict__ gamma, const float* __restrict__ beta,
    const float* __restrict__ mean, const float* __restrict__ var,
    float* __restrict__ G) {
  __shared__ float lds[64 * 65];            // gfeat staging / knn survivor strips
  const int bid = blockIdx.x >> 1;

  if ((blockIdx.x & 1) == 0) {
    // ------------------------------ knn role ------------------------------
    u32* surv = (u32*)lds;
    const int lane = threadIdx.x & 63;
    const int wv = threadIdx.x >> 6;
    const int pid = bid * 4 + wv;           // b*N + i
    const int b = pid >> 11;
    const int i = pid & (NN - 1);
    const float4* Pb = P + ((size_t)b << 11);
    float4 q = Pb[i];
    u32* sv = surv + wv * 64;
    const u64 lml = (1ull << lane) - 1ull;  // lanemask_lt

    u32 du[32];
    u32 m0 = 0xFFFFFFFFu;                   // lane minimum
#pragma unroll
    for (int c = 0; c < 32; ++c) {
      int j = (c << 6) | lane;
      float4 p = Pb[j];
      float dt = refdot3(q.x, q.y, q.z, p.x, p.y, p.z);
      u32 d = __float_as_uint(refdist(q.w, p.w, dt));
      du[c] = d;
      m0 = d < m0 ? d : m0;
    }

    // T = 32nd-smallest lane-minimum (>= D by the theorem)
    u32 Av = m0;
    WAVE_SORT64(Av);
    const u32 T = __shfl(Av, 31);

    // survivor count n = #{du <= T} (wave total)
    u32 cls = 0;
#pragma unroll
    for (int c = 0; c < 32; ++c) cls += (du[c] <= T) ? 1u : 0u;
    u32 ntot = cls;
#pragma unroll
    for (int sft = 1; sft < 64; sft <<= 1) ntot += __shfl_xor(ntot, sft);

    u32 D;
    if (ntot <= 64) {
      u32 base = 0;
#pragma unroll
      for (int c = 0; c < 32; ++c) {
        u64 mk = __ballot(du[c] <= T);
        u32 rk = (u32)__popcll(mk & lml);
        if (du[c] <= T) sv[base + rk] = du[c];
        base += (u32)__popcll(mk);
      }
      u32 x = (lane < (int)ntot) ? sv[lane] : 0xFFFFFFFFu;
      WAVE_SORT64(x);
      D = __shfl(x, 31);                    // exact 32nd smallest overall
    } else {
      u32 ans = 0;
#pragma unroll 1
      for (int bbit = 30; bbit >= 0; --bbit) {
        u32 t2 = ans | (1u << bbit);
        u32 c2 = 0;
#pragma unroll
        for (int c = 0; c < 32; ++c) c2 += (du[c] < t2) ? 1u : 0u;
#pragma unroll
        for (int sft = 1; sft < 64; sft <<= 1) c2 += __shfl_xor(c2, sft);
        if (c2 < KK) ans = t2;
      }
      D = ans;
    }

    // emit du < D at prefix-scanned positions (order arbitrary; set exact)
    u32 cntL = 0;
#pragma unroll
    for (int c = 0; c < 32; ++c) cntL += (du[c] < D) ? 1u : 0u;
    u32 v2 = cntL;
#pragma unroll
    for (int sft = 1; sft < 64; sft <<= 1) {
      u32 o = __shfl_up(v2, sft, 64);
      if (lane >= sft) v2 += o;
    }
    const u32 r = KK - __shfl(v2, 63);      // ties to take at D (>= 1)
    u32 pos = v2 - cntL;
    int* op = idx_out + (size_t)pid * KK;
#pragma unroll
    for (int c = 0; c < 32; ++c) {
      if (du[c] < D) { op[pos] = (c << 6) | lane; ++pos; }
    }
    u32 emit = r;
    u32 wpos = KK - r;
#pragma unroll
    for (int c = 0; c < 32; ++c) {
      if (emit != 0) {
        u64 mk = __ballot(du[c] == D);
        u32 pc = (u32)__popcll(mk);
        u32 rk = (u32)__popcll(mk & lml);
        if ((du[c] == D) && rk < emit) op[wpos + rk] = (c << 6) | lane;
        u32 take = pc < emit ? pc : emit;
        wpos += take;
        emit -= take;
      }
    }
  } else {
    // ----------------------------- gfeat role -----------------------------
    for (int e = threadIdx.x; e < 4096; e += 256) {
      int c = e >> 6, cp = e & 63;
      lds[c * 65 + cp] = conv_w[c * (CC + 3) + 3 + cp];
    }
    __syncthreads();
    int t = bid * 256 + threadIdx.x;        // t = m*64 + c
    int c = t & 63;
    int m = t >> 6;                          // b*N + n
    int b = m >> 11;
    int n = m & (NN - 1);
    float inv = __fdiv_rn(gamma[c], __fsqrt_rn(__fadd_rn(var[c], BN_EPSF)));
    float shift = __fsub_rn(beta[c], __fmul_rn(mean[c], inv));
    const float* f = feats + (size_t)b * CC * NN + n;   // stride NN over c'
    float acc = 0.f;
#pragma unroll
    for (int cp = 0; cp < CC; ++cp) acc = fmaf(lds[c * 65 + cp], f[(size_t)cp * NN], acc);
    G[t] = fmaf(inv, acc, shift);
  }
}

// ---------------------------------------------------------------------------
// Kernel 3: density weights. 8 points per 256-thread block, 32 lanes/point.
// ---------------------------------------------------------------------------
__global__ __launch_bounds__(256) void density_kernel(const float* __restrict__ coords,
                                                      const int* __restrict__ idxb,
                                                      float* __restrict__ wbuf) {
  const int k = threadIdx.x & 31;
  const int sub = threadIdx.x >> 5;            // 0..7
  const int pid = blockIdx.x * 8 + sub;        // b*N + i
  const int b = pid >> 11;
  const float* cb = coords + (size_t)b * NN * 3;
  int j = idxb[(size_t)pid * KK + k];
  float nx = cb[j * 3 + 0], ny = cb[j * 3 + 1], nz = cb[j * 3 + 2];
  float sme = refsq3(nx, ny, nz);

  float d[32];
#pragma unroll
  for (int t = 0; t < 32; ++t) {
    float ox = __shfl(nx, t, 32);
    float oy = __shfl(ny, t, 32);
    float oz = __shfl(nz, t, 32);
    float so = refsq3(ox, oy, oz);
    float dt = refdot3(nx, ny, nz, ox, oy, oz);
    float dd = refdist(sme, so, dt);
    d[t] = (t == k) ? INFINITY : dd;   // eye mask
  }

  // sort 32 f32 ascending (values only; need the 16th smallest VALUE)
#pragma unroll
  for (int p = 1; p < 32; p <<= 1) {
#pragma unroll
    for (int kk = p; kk >= 1; kk >>= 1) {
#pragma unroll
      for (int jj = (kk & (p - 1)); jj + kk < 32; jj += 2 * kk) {
#pragma unroll
        for (int t = 0; t < kk; ++t) {
          if ((t + jj) / (2 * p) == (t + jj + kk) / (2 * p)) {
            float a = d[t + jj], b2 = d[t + jj + kk];
            float lo = fminf(a, b2);
            float hi = fmaxf(a, b2);
            d[t + jj] = lo;
            d[t + jj + kk] = hi;
          }
        }
      }
    }
  }

  float kth = d[DK - 1];
  float r1 = fmaxf(kth, EPSF);
  float raw = __fmul_rn(__fmul_rn(r1, r1), r1);
  float s = raw;
#pragma unroll
  for (int t = 1; t < 32; t <<= 1) s += __shfl_xor(s, t, 32);
  wbuf[(size_t)pid * KK + k] = raw / fmaxf(s, EPSF);
}

// ---------------------------------------------------------------------------
// Kernel 4: aggregation. One wave/point, lane = channel.
// ---------------------------------------------------------------------------
__global__ __launch_bounds__(256) void agg_kernel(
    const float* __restrict__ coords, const float* __restrict__ conv_w,
    const float* __restrict__ gamma, const float* __restrict__ var,
    const float* __restrict__ G, const int* __restrict__ idxb,
    const float* __restrict__ wbuf, float* __restrict__ out) {
  const int lane = threadIdx.x & 63;
  const int wv = threadIdx.x >> 6;
  const int pid = blockIdx.x * 4 + wv;   // b*N + i
  const int b = pid >> 11;
  const int i = pid & (NN - 1);
  const float* cb = coords + (size_t)b * NN * 3;

  float inv = __fdiv_rn(gamma[lane], __fsqrt_rn(__fadd_rn(var[lane], BN_EPSF)));
  float w0 = conv_w[lane * (CC + 3) + 0] * inv;
  float w1 = conv_w[lane * (CC + 3) + 1] * inv;
  float w2 = conv_w[lane * (CC + 3) + 2] * inv;

  float cx = cb[i * 3 + 0], cy = cb[i * 3 + 1], cz = cb[i * 3 + 2];
  float rx = 0.f, ry = 0.f, rz = 0.f, wk = 0.f;
  int jk = 0;
  if (lane < 32) {
    jk = idxb[(size_t)pid * KK + lane];
    rx = __fdiv_rn(__fsub_rn(cb[jk * 3 + 0], cx), RADIUSF);
    ry = __fdiv_rn(__fsub_rn(cb[jk * 3 + 1], cy), RADIUSF);
    rz = __fdiv_rn(__fsub_rn(cb[jk * 3 + 2], cz), RADIUSF);
    wk = wbuf[(size_t)pid * KK + lane];
  }

  float acc = 0.f;
#pragma unroll
  for (int k = 0; k < KK; ++k) {
    int j = __shfl(jk, k);
    float sx = __shfl(rx, k);
    float sy = __shfl(ry, k);
    float sz = __shfl(rz, k);
    float sw = __shfl(wk, k);
    float g = G[((size_t)(b * NN + j)) * 64 + lane];
    float y = fmaf(w2, sz, fmaf(w1, sy, fmaf(w0, sx, g)));
    y = fmaxf(y, 0.f);
    acc = fmaf(sw, y, acc);
  }
  out[((size_t)(b * 64 + lane)) * NN + i] = acc;
}

// ---------------------------------------------------------------------------
extern "C" void kernel_launch(void* const* d_in, const int* in_sizes, int n_in,
                              void* d_out, int out_size, void* d_ws, size_t ws_size,
                              hipStream_t stream) {
  const float* coords = (const float*)d_in[0];
  const float* feats  = (const float*)d_in[1];
  const float* conv_w = (const float*)d_in[2];
  const float* gamma  = (const float*)d_in[3];
  const float* beta   = (const float*)d_in[4];
  const float* mean   = (const float*)d_in[5];
  const float* var    = (const float*)d_in[6];
  float* out = (float*)d_out;

  int*   idxb = (int*)d_ws;                                          // 2 MB
  float* wbuf = (float*)((char*)d_ws + (size_t)2 * 1024 * 1024);     // 2 MB
  float* G    = (float*)((char*)d_ws + (size_t)4 * 1024 * 1024);     // 4 MB
  // P lives in the first 256 KB of the wbuf region: dead before density
  // writes wbuf, and NOT aliased with G (mega runs knn-reads-P concurrent
  // with gfeat-writes-G).
  float4* P   = (float4*)wbuf;                                       // 256 KB

  const int NPTS = BB * NN;   // 16384

  pack_kernel<<<NPTS / 256, 256, 0, stream>>>(coords, P);
  // even blocks: knn (NPTS/4 = 4096 blocks); odd blocks: gfeat (4096 blocks)
  mega_kernel<<<2 * (NPTS / 4), 256, 0, stream>>>(P, idxb, feats, conv_w, gamma,
                                                  beta, mean, var, G);
  density_kernel<<<NPTS / 8, 256, 0, stream>>>(coords, idxb, wbuf);
  agg_kernel<<<NPTS / 4, 256, 0, stream>>>(coords, conv_w, gamma, var, G, idxb,
                                           wbuf, out);
}

// Round 14
// 113.682 us; speedup vs baseline: 1.1465x; 1.1465x over previous
//
#include <hip/hip_runtime.h>
#include <stdint.h>

#define BB 8
#define NN 2048
#define CC 64
#define KK 32
#define DK 16
#define RADIUSF 0.2f
#define EPSF 1e-8f
#define BN_EPSF 1e-5f

typedef unsigned long long u64;
typedef unsigned int u32;

// --- fp32 helpers matching the reference's arithmetic ---
__device__ __forceinline__ float refsq3(float a, float b, float c) {
  return __fadd_rn(__fadd_rn(__fmul_rn(a, a), __fmul_rn(b, b)), __fmul_rn(c, c));
}
__device__ __forceinline__ float refdot3(float ax, float ay, float az,
                                         float bx, float by, float bz) {
  return __builtin_fmaf(az, bz, __builtin_fmaf(ay, by, __fmul_rn(ax, bx)));
}
__device__ __forceinline__ float refdist(float sx, float sy, float dt) {
  float d2 = __fsub_rn(__fadd_rn(sx, sy), __fmul_rn(2.0f, dt));
  d2 = fmaxf(d2, 0.0f);
  return d2 > 0.0f ? __fsqrt_rn(d2) : 0.0f;
}

// cross-lane bitonic sort of one u32 per lane, ascending by lane index
#define WAVE_SORT64(V)                                                        \
  {                                                                           \
    _Pragma("unroll") for (int k_ = 2; k_ <= 64; k_ <<= 1) {                  \
      _Pragma("unroll") for (int j_ = k_ >> 1; j_ >= 1; j_ >>= 1) {           \
        u32 o_ = __shfl_xor(V, j_);                                           \
        bool keepmin_ = ((lane & k_) == 0) == ((lane & j_) == 0);             \
        u32 mn_ = V < o_ ? V : o_;                                            \
        u32 mx_ = V < o_ ? o_ : V;                                            \
        V = keepmin_ ? mn_ : mx_;                                             \
      }                                                                       \
    }                                                                         \
  }

// ---------------------------------------------------------------------------
// Kernel 0: pack coords + exact ref-rounded sq-norm into float4 (x,y,z,sn).
// ---------------------------------------------------------------------------
__global__ __launch_bounds__(256) void pack_kernel(const float* __restrict__ coords,
                                                   float4* __restrict__ P) {
  int t = blockIdx.x * 256 + threadIdx.x;   // 0..16383
  float x = coords[t * 3 + 0], y = coords[t * 3 + 1], z = coords[t * 3 + 2];
  P[t] = make_float4(x, y, z, refsq3(x, y, z));
}

// ---------------------------------------------------------------------------
// Kernel 1: G[b][n][c] = inv[c]*(W_f[c,:]·feats[b,:,n]) + shift[c]
// (separate from knn on the stream: r13 showed co-scheduling evicts knn's
// L1-resident P and regresses 17 us — cache-antagonistic roles stay apart)
// ---------------------------------------------------------------------------
__global__ __launch_bounds__(256) void gfeat_kernel(
    const float* __restrict__ feats, const float* __restrict__ conv_w,
    const float* __restrict__ gamma, const float* __restrict__ beta,
    const float* __restrict__ mean, const float* __restrict__ var,
    float* __restrict__ G) {
  __shared__ float wlds[64 * 65];
  for (int e = threadIdx.x; e < 4096; e += 256) {
    int c = e >> 6, cp = e & 63;
    wlds[c * 65 + cp] = conv_w[c * (CC + 3) + 3 + cp];
  }
  __syncthreads();
  int t = blockIdx.x * 256 + threadIdx.x;   // t = m*64 + c
  int c = t & 63;
  int m = t >> 6;                            // b*N + n
  int b = m >> 11;
  int n = m & (NN - 1);
  float inv = __fdiv_rn(gamma[c], __fsqrt_rn(__fadd_rn(var[c], BN_EPSF)));
  float shift = __fsub_rn(beta[c], __fmul_rn(mean[c], inv));
  const float* f = feats + (size_t)b * CC * NN + n;   // stride NN over c'
  float acc = 0.f;
#pragma unroll
  for (int cp = 0; cp < CC; ++cp) acc = fmaf(wlds[c * 65 + cp], f[(size_t)cp * NN], acc);
  G[t] = fmaf(inv, acc, shift);
}

// ---------------------------------------------------------------------------
// Kernel 2: exact KNN-SET, threshold prefilter + survivor select (r12 body,
// proven). T = A[31] of sorted lane-minima (theorem: at most 31 lane-minima
// < D => A[31] >= D). NEW r14: tie fast-path — when #{du <= D} == 32 (no tie
// at the boundary; the common case for continuous distances) emit in one
// scan loop, skipping the 32-iter ballot tie machinery.
// ---------------------------------------------------------------------------
__global__ __launch_bounds__(256) void knn_kernel(const float4* __restrict__ P,
                                                  int* __restrict__ idx_out) {
  __shared__ u32 surv[4 * 64];              // wave-private survivor strips
  const int lane = threadIdx.x & 63;
  const int wv = threadIdx.x >> 6;
  const int pid = blockIdx.x * 4 + wv;      // b*N + i
  const int b = pid >> 11;
  const int i = pid & (NN - 1);
  const float4* Pb = P + ((size_t)b << 11);
  float4 q = Pb[i];
  u32* sv = surv + wv * 64;
  const u64 lml = (1ull << lane) - 1ull;    // lanemask_lt

  u32 du[32];
  u32 m0 = 0xFFFFFFFFu;                     // lane minimum
#pragma unroll
  for (int c = 0; c < 32; ++c) {
    int j = (c << 6) | lane;
    float4 p = Pb[j];
    float dt = refdot3(q.x, q.y, q.z, p.x, p.y, p.z);
    u32 d = __float_as_uint(refdist(q.w, p.w, dt));
    du[c] = d;
    m0 = d < m0 ? d : m0;
  }

  // T = 32nd-smallest lane-minimum (>= D by the theorem)
  u32 Av = m0;
  WAVE_SORT64(Av);
  const u32 T = __shfl(Av, 31);

  // survivor count n = #{du <= T} (wave total)
  u32 cls = 0;
#pragma unroll
  for (int c = 0; c < 32; ++c) cls += (du[c] <= T) ? 1u : 0u;
  u32 ntot = cls;
#pragma unroll
  for (int sft = 1; sft < 64; sft <<= 1) ntot += __shfl_xor(ntot, sft);

  u32 D;
  if (ntot <= 64) {
    u32 base = 0;
#pragma unroll
    for (int c = 0; c < 32; ++c) {
      u64 mk = __ballot(du[c] <= T);
      u32 rk = (u32)__popcll(mk & lml);
      if (du[c] <= T) sv[base + rk] = du[c];
      base += (u32)__popcll(mk);
    }
    u32 x = (lane < (int)ntot) ? sv[lane] : 0xFFFFFFFFu;
    WAVE_SORT64(x);
    D = __shfl(x, 31);                      // exact 32nd smallest overall
  } else {
    // exact bit-descent fallback (rare): largest ans with #{du < ans} < 32
    u32 ans = 0;
#pragma unroll 1
    for (int bbit = 30; bbit >= 0; --bbit) {
      u32 t2 = ans | (1u << bbit);
      u32 c2 = 0;
#pragma unroll
      for (int c = 0; c < 32; ++c) c2 += (du[c] < t2) ? 1u : 0u;
#pragma unroll
      for (int sft = 1; sft < 64; sft <<= 1) c2 += __shfl_xor(c2, sft);
      if (c2 < KK) ans = t2;
    }
    D = ans;
  }

  int* op = idx_out + (size_t)pid * KK;

  // fast path: no tie at the boundary -> #{du <= D} == 32, single emit loop
  u32 cLE = 0;
#pragma unroll
  for (int c = 0; c < 32; ++c) cLE += (du[c] <= D) ? 1u : 0u;
  u32 vLE = cLE;
#pragma unroll
  for (int sft = 1; sft < 64; sft <<= 1) {
    u32 o = __shfl_up(vLE, sft, 64);
    if (lane >= sft) vLE += o;
  }
  if (__shfl(vLE, 63) == KK) {
    u32 pos = vLE - cLE;
#pragma unroll
    for (int c = 0; c < 32; ++c) {
      if (du[c] <= D) { op[pos] = (c << 6) | lane; ++pos; }
    }
  } else {
    // slow path (boundary tie): du<D via scan, ties via ballot rank (j asc)
    u32 cntL = 0;
#pragma unroll
    for (int c = 0; c < 32; ++c) cntL += (du[c] < D) ? 1u : 0u;
    u32 v2 = cntL;
#pragma unroll
    for (int sft = 1; sft < 64; sft <<= 1) {
      u32 o = __shfl_up(v2, sft, 64);
      if (lane >= sft) v2 += o;
    }
    const u32 r = KK - __shfl(v2, 63);      // ties to take at D (>= 1)
    u32 pos = v2 - cntL;
#pragma unroll
    for (int c = 0; c < 32; ++c) {
      if (du[c] < D) { op[pos] = (c << 6) | lane; ++pos; }
    }
    u32 emit = r;
    u32 wpos = KK - r;
#pragma unroll
    for (int c = 0; c < 32; ++c) {
      if (emit != 0) {
        u64 mk = __ballot(du[c] == D);
        u32 pc = (u32)__popcll(mk);
        u32 rk = (u32)__popcll(mk & lml);
        if ((du[c] == D) && rk < emit) op[wpos + rk] = (c << 6) | lane;
        u32 take = pc < emit ? pc : emit;
        wpos += take;
        emit -= take;
      }
    }
  }
}

// ---------------------------------------------------------------------------
// Kernel 3: fused density + aggregation. One wave per point.
// Layout trick: lane k holds neighbor k (upper half duplicates via width-32
// shfls -> no divergence), so density leaves w_k in lane k — exactly where
// agg's __shfl(wk, k) expects it. Neighbor loads are one float4 from P
// (coords + exact refsq3 norm from pack); rel reuses the same registers.
// Density sorts u32 d^2-bits (monotone => identical 16th VALUE), one sqrt at
// the end. Then agg: lane = channel, 32 gathered G rows + fused BN/ReLU.
// Kills the separate density kernel, the 2 MB wbuf round-trip, one launch.
// ---------------------------------------------------------------------------
__global__ __launch_bounds__(256) void dagg_kernel(
    const float4* __restrict__ P, const float* __restrict__ conv_w,
    const float* __restrict__ gamma, const float* __restrict__ var,
    const float* __restrict__ G, const int* __restrict__ idxb,
    float* __restrict__ out) {
  const int lane = threadIdx.x & 63;
  const int wv = threadIdx.x >> 6;
  const int pid = blockIdx.x * 4 + wv;   // b*N + i
  const int b = pid >> 11;
  const int i = pid & (NN - 1);
  const int k = lane & 31;
  const float4* Pb = P + ((size_t)b << 11);

  float4 q = Pb[i];                       // query point (wave-uniform)
  int jk = idxb[(size_t)pid * KK + k];    // neighbor index (dup in upper half)
  float4 nb = Pb[jk];                     // neighbor coords + refsq3 norm

  // rel for agg (lane k): (n - c)/R, ref rounding
  float rx = __fdiv_rn(__fsub_rn(nb.x, q.x), RADIUSF);
  float ry = __fdiv_rn(__fsub_rn(nb.y, q.y), RADIUSF);
  float rz = __fdiv_rn(__fsub_rn(nb.z, q.z), RADIUSF);

  // --- density phase: gd[k][t] over the 32 neighbors, need 16th smallest ---
  u32 d2b[32];
#pragma unroll
  for (int t = 0; t < 32; ++t) {
    float ox = __shfl(nb.x, t, 32);
    float oy = __shfl(nb.y, t, 32);
    float oz = __shfl(nb.z, t, 32);
    float so = __shfl(nb.w, t, 32);
    float dt = refdot3(nb.x, nb.y, nb.z, ox, oy, oz);
    float d2 = __fsub_rn(__fadd_rn(nb.w, so), __fmul_rn(2.0f, dt));
    d2 = fmaxf(d2, 0.0f);
    d2b[t] = (t == k) ? 0x7F800000u : __float_as_uint(d2);  // eye = +inf
  }
  // Batcher sort 32 u32 ascending (d2 bits monotone in d; kth VALUE commutes
  // with the monotone sqrt)
#pragma unroll
  for (int p = 1; p < 32; p <<= 1) {
#pragma unroll
    for (int kk = p; kk >= 1; kk >>= 1) {
#pragma unroll
      for (int jj = (kk & (p - 1)); jj + kk < 32; jj += 2 * kk) {
#pragma unroll
        for (int t = 0; t < kk; ++t) {
          if ((t + jj) / (2 * p) == (t + jj + kk) / (2 * p)) {
            u32 a = d2b[t + jj], b2 = d2b[t + jj + kk];
            d2b[t + jj] = a < b2 ? a : b2;
            d2b[t + jj + kk] = a < b2 ? b2 : a;
          }
        }
      }
    }
  }
  float kd2 = __uint_as_float(d2b[DK - 1]);
  float kth = kd2 > 0.f ? __fsqrt_rn(kd2) : 0.f;
  float r1 = fmaxf(kth, EPSF);
  float raw = __fmul_rn(__fmul_rn(r1, r1), r1);
  float s = raw;
#pragma unroll
  for (int t = 1; t < 32; t <<= 1) s += __shfl_xor(s, t, 32);
  float wk = raw / fmaxf(s, EPSF);        // w_k now lives in lane k ✓

  // --- agg phase: lane = channel ---
  float inv = __fdiv_rn(gamma[lane], __fsqrt_rn(__fadd_rn(var[lane], BN_EPSF)));
  float w0 = conv_w[lane * (CC + 3) + 0] * inv;
  float w1 = conv_w[lane * (CC + 3) + 1] * inv;
  float w2 = conv_w[lane * (CC + 3) + 2] * inv;

  float acc = 0.f;
#pragma unroll
  for (int kk2 = 0; kk2 < KK; ++kk2) {
    int j = __shfl(jk, kk2);              // lane kk2 (lower half) holds k=kk2
    float sx = __shfl(rx, kk2);
    float sy = __shfl(ry, kk2);
    float sz = __shfl(rz, kk2);
    float sw = __shfl(wk, kk2);
    float g = G[((size_t)(b * NN + j)) * 64 + lane];
    float y = fmaf(w2, sz, fmaf(w1, sy, fmaf(w0, sx, g)));
    y = fmaxf(y, 0.f);
    acc = fmaf(sw, y, acc);
  }
  out[((size_t)(b * 64 + lane)) * NN + i] = acc;
}

// ---------------------------------------------------------------------------
extern "C" void kernel_launch(void* const* d_in, const int* in_sizes, int n_in,
                              void* d_out, int out_size, void* d_ws, size_t ws_size,
                              hipStream_t stream) {
  const float* coords = (const float*)d_in[0];
  const float* feats  = (const float*)d_in[1];
  const float* conv_w = (const float*)d_in[2];
  const float* gamma  = (const float*)d_in[3];
  const float* beta   = (const float*)d_in[4];
  const float* mean   = (const float*)d_in[5];
  const float* var    = (const float*)d_in[6];
  float* out = (float*)d_out;

  int*   idxb = (int*)d_ws;                                          // 2 MB
  float4* P   = (float4*)((char*)d_ws + (size_t)2 * 1024 * 1024);    // 256 KB
  float* G    = (float*)((char*)d_ws + (size_t)4 * 1024 * 1024);     // 4 MB

  const int NPTS = BB * NN;   // 16384

  pack_kernel<<<NPTS / 256, 256, 0, stream>>>(coords, P);
  knn_kernel<<<NPTS / 4, 256, 0, stream>>>(P, idxb);
  gfeat_kernel<<<(NPTS * CC) / 256, 256, 0, stream>>>(feats, conv_w, gamma, beta,
                                                      mean, var, G);
  dagg_kernel<<<NPTS / 4, 256, 0, stream>>>(P, conv_w, gamma, var, G, idxb, out);
}

// Round 15
// 102.937 us; speedup vs baseline: 1.2661x; 1.1044x over previous
//
#include <hip/hip_runtime.h>
#include <stdint.h>

#define BB 8
#define NN 2048
#define CC 64
#define KK 32
#define DK 16
#define RADIUSF 0.2f
#define EPSF 1e-8f
#define BN_EPSF 1e-5f

typedef unsigned long long u64;
typedef unsigned int u32;

// --- fp32 helpers matching the reference's arithmetic ---
__device__ __forceinline__ float refsq3(float a, float b, float c) {
  return __fadd_rn(__fadd_rn(__fmul_rn(a, a), __fmul_rn(b, b)), __fmul_rn(c, c));
}
__device__ __forceinline__ float refdot3(float ax, float ay, float az,
                                         float bx, float by, float bz) {
  return __builtin_fmaf(az, bz, __builtin_fmaf(ay, by, __fmul_rn(ax, bx)));
}
__device__ __forceinline__ float refdist(float sx, float sy, float dt) {
  float d2 = __fsub_rn(__fadd_rn(sx, sy), __fmul_rn(2.0f, dt));
  d2 = fmaxf(d2, 0.0f);
  return d2 > 0.0f ? __fsqrt_rn(d2) : 0.0f;
}

// cross-lane bitonic sort of one u32 per lane, ascending by lane index
#define WAVE_SORT64(V)                                                        \
  {                                                                           \
    _Pragma("unroll") for (int k_ = 2; k_ <= 64; k_ <<= 1) {                  \
      _Pragma("unroll") for (int j_ = k_ >> 1; j_ >= 1; j_ >>= 1) {           \
        u32 o_ = __shfl_xor(V, j_);                                           \
        bool keepmin_ = ((lane & k_) == 0) == ((lane & j_) == 0);             \
        u32 mn_ = V < o_ ? V : o_;                                            \
        u32 mx_ = V < o_ ? o_ : V;                                            \
        V = keepmin_ ? mn_ : mx_;                                             \
      }                                                                       \
    }                                                                         \
  }

// ---------------------------------------------------------------------------
// Kernel 0: pack coords + exact ref-rounded sq-norm into float4 (x,y,z,sn).
// ---------------------------------------------------------------------------
__global__ __launch_bounds__(256) void pack_kernel(const float* __restrict__ coords,
                                                   float4* __restrict__ P) {
  int t = blockIdx.x * 256 + threadIdx.x;   // 0..16383
  float x = coords[t * 3 + 0], y = coords[t * 3 + 1], z = coords[t * 3 + 2];
  P[t] = make_float4(x, y, z, refsq3(x, y, z));
}

// ---------------------------------------------------------------------------
// Kernel 1: G[b][n][c] = inv[c]*(W_f[c,:]·feats[b,:,n]) + shift[c]
// (kept separate from knn: r13 showed co-scheduling evicts knn's L1-resident
// P and regresses — cache-antagonistic roles stay apart)
// ---------------------------------------------------------------------------
__global__ __launch_bounds__(256) void gfeat_kernel(
    const float* __restrict__ feats, const float* __restrict__ conv_w,
    const float* __restrict__ gamma, const float* __restrict__ beta,
    const float* __restrict__ mean, const float* __restrict__ var,
    float* __restrict__ G) {
  __shared__ float wlds[64 * 65];
  for (int e = threadIdx.x; e < 4096; e += 256) {
    int c = e >> 6, cp = e & 63;
    wlds[c * 65 + cp] = conv_w[c * (CC + 3) + 3 + cp];
  }
  __syncthreads();
  int t = blockIdx.x * 256 + threadIdx.x;   // t = m*64 + c
  int c = t & 63;
  int m = t >> 6;                            // b*N + n
  int b = m >> 11;
  int n = m & (NN - 1);
  float inv = __fdiv_rn(gamma[c], __fsqrt_rn(__fadd_rn(var[c], BN_EPSF)));
  float shift = __fsub_rn(beta[c], __fmul_rn(mean[c], inv));
  const float* f = feats + (size_t)b * CC * NN + n;   // stride NN over c'
  float acc = 0.f;
#pragma unroll
  for (int cp = 0; cp < CC; ++cp) acc = fmaf(wlds[c * 65 + cp], f[(size_t)cp * NN], acc);
  G[t] = fmaf(inv, acc, shift);
}

// ---------------------------------------------------------------------------
// Kernel 2: exact KNN-SET, threshold prefilter + survivor select (r12 body +
// r14 tie fast-path, both proven). T = A[31] of sorted lane-minima.
// ---------------------------------------------------------------------------
__global__ __launch_bounds__(256) void knn_kernel(const float4* __restrict__ P,
                                                  int* __restrict__ idx_out) {
  __shared__ u32 surv[4 * 64];              // wave-private survivor strips
  const int lane = threadIdx.x & 63;
  const int wv = threadIdx.x >> 6;
  const int pid = blockIdx.x * 4 + wv;      // b*N + i
  const int b = pid >> 11;
  const int i = pid & (NN - 1);
  const float4* Pb = P + ((size_t)b << 11);
  float4 q = Pb[i];
  u32* sv = surv + wv * 64;
  const u64 lml = (1ull << lane) - 1ull;    // lanemask_lt

  u32 du[32];
  u32 m0 = 0xFFFFFFFFu;                     // lane minimum
#pragma unroll
  for (int c = 0; c < 32; ++c) {
    int j = (c << 6) | lane;
    float4 p = Pb[j];
    float dt = refdot3(q.x, q.y, q.z, p.x, p.y, p.z);
    u32 d = __float_as_uint(refdist(q.w, p.w, dt));
    du[c] = d;
    m0 = d < m0 ? d : m0;
  }

  // T = 32nd-smallest lane-minimum (>= D: at most 31 lane-minima < D)
  u32 Av = m0;
  WAVE_SORT64(Av);
  const u32 T = __shfl(Av, 31);

  // survivor count n = #{du <= T} (wave total)
  u32 cls = 0;
#pragma unroll
  for (int c = 0; c < 32; ++c) cls += (du[c] <= T) ? 1u : 0u;
  u32 ntot = cls;
#pragma unroll
  for (int sft = 1; sft < 64; sft <<= 1) ntot += __shfl_xor(ntot, sft);

  u32 D;
  if (ntot <= 64) {
    u32 base = 0;
#pragma unroll
    for (int c = 0; c < 32; ++c) {
      u64 mk = __ballot(du[c] <= T);
      u32 rk = (u32)__popcll(mk & lml);
      if (du[c] <= T) sv[base + rk] = du[c];
      base += (u32)__popcll(mk);
    }
    u32 x = (lane < (int)ntot) ? sv[lane] : 0xFFFFFFFFu;
    WAVE_SORT64(x);
    D = __shfl(x, 31);                      // exact 32nd smallest overall
  } else {
    // exact bit-descent fallback (rare): largest ans with #{du < ans} < 32
    u32 ans = 0;
#pragma unroll 1
    for (int bbit = 30; bbit >= 0; --bbit) {
      u32 t2 = ans | (1u << bbit);
      u32 c2 = 0;
#pragma unroll
      for (int c = 0; c < 32; ++c) c2 += (du[c] < t2) ? 1u : 0u;
#pragma unroll
      for (int sft = 1; sft < 64; sft <<= 1) c2 += __shfl_xor(c2, sft);
      if (c2 < KK) ans = t2;
    }
    D = ans;
  }

  int* op = idx_out + (size_t)pid * KK;

  // fast path: no tie at the boundary -> #{du <= D} == 32, single emit loop
  u32 cLE = 0;
#pragma unroll
  for (int c = 0; c < 32; ++c) cLE += (du[c] <= D) ? 1u : 0u;
  u32 vLE = cLE;
#pragma unroll
  for (int sft = 1; sft < 64; sft <<= 1) {
    u32 o = __shfl_up(vLE, sft, 64);
    if (lane >= sft) vLE += o;
  }
  if (__shfl(vLE, 63) == KK) {
    u32 pos = vLE - cLE;
#pragma unroll
    for (int c = 0; c < 32; ++c) {
      if (du[c] <= D) { op[pos] = (c << 6) | lane; ++pos; }
    }
  } else {
    // slow path (boundary tie): du<D via scan, ties via ballot rank (j asc)
    u32 cntL = 0;
#pragma unroll
    for (int c = 0; c < 32; ++c) cntL += (du[c] < D) ? 1u : 0u;
    u32 v2 = cntL;
#pragma unroll
    for (int sft = 1; sft < 64; sft <<= 1) {
      u32 o = __shfl_up(v2, sft, 64);
      if (lane >= sft) v2 += o;
    }
    const u32 r = KK - __shfl(v2, 63);      // ties to take at D (>= 1)
    u32 pos = v2 - cntL;
#pragma unroll
    for (int c = 0; c < 32; ++c) {
      if (du[c] < D) { op[pos] = (c << 6) | lane; ++pos; }
    }
    u32 emit = r;
    u32 wpos = KK - r;
#pragma unroll
    for (int c = 0; c < 32; ++c) {
      if (emit != 0) {
        u64 mk = __ballot(du[c] == D);
        u32 pc = (u32)__popcll(mk);
        u32 rk = (u32)__popcll(mk & lml);
        if ((du[c] == D) && rk < emit) op[wpos + rk] = (c << 6) | lane;
        u32 take = pc < emit ? pc : emit;
        wpos += take;
        emit -= take;
      }
    }
  }
}

// ---------------------------------------------------------------------------
// Kernel 3: fused density + aggregation, TWO points per wave (r14 regression
// fix: 1 point/wave duplicated the 191-CE density sort across wave halves,
// doubling total sort work vs the old density_kernel).
// Density: lanes 0-31 = point A's neighbors, lanes 32-63 = point B's
// (width-32 shfls confine traffic within halves; math byte-identical to the
// proven density_kernel, on u32 d^2 bits — monotone => identical 16th VALUE).
// Agg: both points sequentially, all 64 lanes = channels; w_k / rel_k / j_k
// read via width-64 shfl from lane half*32+k where density left them.
// ---------------------------------------------------------------------------
__global__ __launch_bounds__(256) void dagg_kernel(
    const float4* __restrict__ P, const float* __restrict__ conv_w,
    const float* __restrict__ gamma, const float* __restrict__ var,
    const float* __restrict__ G, const int* __restrict__ idxb,
    float* __restrict__ out) {
  const int lane = threadIdx.x & 63;
  const int wv = threadIdx.x >> 6;
  const int half = lane >> 5;
  const int k = lane & 31;
  const int pid_pair = blockIdx.x * 8 + wv * 2;   // even; never crosses batch
  const int pid = pid_pair + half;                 // this half's point
  const int b = pid >> 11;
  const float4* Pb = P + ((size_t)b << 11);

  const int i = pid & (NN - 1);
  float4 q = Pb[i];                       // broadcast within each half
  int jk = idxb[(size_t)pid * KK + k];    // neighbor index (lane half*32+k)
  float4 nb = Pb[jk];                     // neighbor coords + refsq3 norm

  // rel for agg: (n - c)/R, ref rounding
  float rx = __fdiv_rn(__fsub_rn(nb.x, q.x), RADIUSF);
  float ry = __fdiv_rn(__fsub_rn(nb.y, q.y), RADIUSF);
  float rz = __fdiv_rn(__fsub_rn(nb.z, q.z), RADIUSF);

  // --- density phase (per half): 16th smallest of 32 neighbor-distances ---
  u32 d2b[32];
#pragma unroll
  for (int t = 0; t < 32; ++t) {
    float ox = __shfl(nb.x, t, 32);
    float oy = __shfl(nb.y, t, 32);
    float oz = __shfl(nb.z, t, 32);
    float so = __shfl(nb.w, t, 32);
    float dt = refdot3(nb.x, nb.y, nb.z, ox, oy, oz);
    float d2 = __fsub_rn(__fadd_rn(nb.w, so), __fmul_rn(2.0f, dt));
    d2 = fmaxf(d2, 0.0f);
    d2b[t] = (t == k) ? 0x7F800000u : __float_as_uint(d2);  // eye = +inf
  }
  // Batcher sort 32 u32 ascending
#pragma unroll
  for (int p = 1; p < 32; p <<= 1) {
#pragma unroll
    for (int kk = p; kk >= 1; kk >>= 1) {
#pragma unroll
      for (int jj = (kk & (p - 1)); jj + kk < 32; jj += 2 * kk) {
#pragma unroll
        for (int t = 0; t < kk; ++t) {
          if ((t + jj) / (2 * p) == (t + jj + kk) / (2 * p)) {
            u32 a = d2b[t + jj], b2 = d2b[t + jj + kk];
            d2b[t + jj] = a < b2 ? a : b2;
            d2b[t + jj + kk] = a < b2 ? b2 : a;
          }
        }
      }
    }
  }
  float kd2 = __uint_as_float(d2b[DK - 1]);
  float kth = kd2 > 0.f ? __fsqrt_rn(kd2) : 0.f;
  float r1 = fmaxf(kth, EPSF);
  float raw = __fmul_rn(__fmul_rn(r1, r1), r1);
  float s = raw;
#pragma unroll
  for (int t = 1; t < 32; t <<= 1) s += __shfl_xor(s, t, 32);
  float wk = raw / fmaxf(s, EPSF);        // w_k in lane half*32+k ✓

  // --- agg phase: lane = channel; two points sequentially ---
  float inv = __fdiv_rn(gamma[lane], __fsqrt_rn(__fadd_rn(var[lane], BN_EPSF)));
  float w0 = conv_w[lane * (CC + 3) + 0] * inv;
  float w1 = conv_w[lane * (CC + 3) + 1] * inv;
  float w2 = conv_w[lane * (CC + 3) + 2] * inv;

#pragma unroll
  for (int h2 = 0; h2 < 2; ++h2) {
    const int pid2 = pid_pair + h2;
    const int i2 = pid2 & (NN - 1);
    float acc = 0.f;
#pragma unroll
    for (int kk2 = 0; kk2 < KK; ++kk2) {
      int src = h2 * 32 + kk2;            // lane holding this point's k=kk2
      int j = __shfl(jk, src);
      float sx = __shfl(rx, src);
      float sy = __shfl(ry, src);
      float sz = __shfl(rz, src);
      float sw = __shfl(wk, src);
      float g = G[((size_t)(b * NN + j)) * 64 + lane];
      float y = fmaf(w2, sz, fmaf(w1, sy, fmaf(w0, sx, g)));
      y = fmaxf(y, 0.f);
      acc = fmaf(sw, y, acc);
    }
    out[((size_t)(b * 64 + lane)) * NN + i2] = acc;
  }
}

// ---------------------------------------------------------------------------
extern "C" void kernel_launch(void* const* d_in, const int* in_sizes, int n_in,
                              void* d_out, int out_size, void* d_ws, size_t ws_size,
                              hipStream_t stream) {
  const float* coords = (const float*)d_in[0];
  const float* feats  = (const float*)d_in[1];
  const float* conv_w = (const float*)d_in[2];
  const float* gamma  = (const float*)d_in[3];
  const float* beta   = (const float*)d_in[4];
  const float* mean   = (const float*)d_in[5];
  const float* var    = (const float*)d_in[6];
  float* out = (float*)d_out;

  int*   idxb = (int*)d_ws;                                          // 2 MB
  float4* P   = (float4*)((char*)d_ws + (size_t)2 * 1024 * 1024);    // 256 KB
  float* G    = (float*)((char*)d_ws + (size_t)4 * 1024 * 1024);     // 4 MB

  const int NPTS = BB * NN;   // 16384

  pack_kernel<<<NPTS / 256, 256, 0, stream>>>(coords, P);
  knn_kernel<<<NPTS / 4, 256, 0, stream>>>(P, idxb);
  gfeat_kernel<<<(NPTS * CC) / 256, 256, 0, stream>>>(feats, conv_w, gamma, beta,
                                                      mean, var, G);
  dagg_kernel<<<NPTS / 8, 256, 0, stream>>>(P, conv_w, gamma, var, G, idxb, out);
}

// Round 16
// 81.650 us; speedup vs baseline: 1.5962x; 1.2607x over previous
//
#include <hip/hip_runtime.h>
#include <stdint.h>

#define BB 8
#define NN 2048
#define CC 64
#define KK 32
#define DK 16
#define RADIUSF 0.2f
#define EPSF 1e-8f
#define BN_EPSF 1e-5f

typedef unsigned long long u64;
typedef unsigned int u32;

// --- fp32 helpers matching the reference's arithmetic ---
__device__ __forceinline__ float refsq3(float a, float b, float c) {
  return __fadd_rn(__fadd_rn(__fmul_rn(a, a), __fmul_rn(b, b)), __fmul_rn(c, c));
}
__device__ __forceinline__ float refdot3(float ax, float ay, float az,
                                         float bx, float by, float bz) {
  return __builtin_fmaf(az, bz, __builtin_fmaf(ay, by, __fmul_rn(ax, bx)));
}
__device__ __forceinline__ float refdist(float sx, float sy, float dt) {
  float d2 = __fsub_rn(__fadd_rn(sx, sy), __fmul_rn(2.0f, dt));
  d2 = fmaxf(d2, 0.0f);
  return d2 > 0.0f ? __fsqrt_rn(d2) : 0.0f;
}

// cross-lane bitonic sort of one value per lane, ascending by lane (type-generic)
#define WAVE_SORT64(V)                                                        \
  {                                                                           \
    _Pragma("unroll") for (int k_ = 2; k_ <= 64; k_ <<= 1) {                  \
      _Pragma("unroll") for (int j_ = k_ >> 1; j_ >= 1; j_ >>= 1) {           \
        __typeof__(V) o_ = __shfl_xor(V, j_);                                 \
        bool keepmin_ = ((lane & k_) == 0) == ((lane & j_) == 0);             \
        __typeof__(V) mn_ = V < o_ ? V : o_;                                  \
        __typeof__(V) mx_ = V < o_ ? o_ : V;                                  \
        V = keepmin_ ? mn_ : mx_;                                             \
      }                                                                       \
    }                                                                         \
  }

// ---------------------------------------------------------------------------
// Kernel 0: pack coords + exact ref-rounded sq-norm into float4 (x,y,z,sn).
// ---------------------------------------------------------------------------
__global__ __launch_bounds__(256) void pack_kernel(const float* __restrict__ coords,
                                                   float4* __restrict__ P) {
  int t = blockIdx.x * 256 + threadIdx.x;   // 0..16383
  float x = coords[t * 3 + 0], y = coords[t * 3 + 1], z = coords[t * 3 + 2];
  P[t] = make_float4(x, y, z, refsq3(x, y, z));
}

// ---------------------------------------------------------------------------
// Kernel 1: G[b][n][c] = inv[c]*(W_f[c,:]·feats[b,:,n]) + shift[c]
// (kept separate from knn: r13 showed co-scheduling evicts knn's L1-resident
// P and regresses — cache-antagonistic roles stay apart)
// ---------------------------------------------------------------------------
__global__ __launch_bounds__(256) void gfeat_kernel(
    const float* __restrict__ feats, const float* __restrict__ conv_w,
    const float* __restrict__ gamma, const float* __restrict__ beta,
    const float* __restrict__ mean, const float* __restrict__ var,
    float* __restrict__ G) {
  __shared__ float wlds[64 * 65];
  for (int e = threadIdx.x; e < 4096; e += 256) {
    int c = e >> 6, cp = e & 63;
    wlds[c * 65 + cp] = conv_w[c * (CC + 3) + 3 + cp];
  }
  __syncthreads();
  int t = blockIdx.x * 256 + threadIdx.x;   // t = m*64 + c
  int c = t & 63;
  int m = t >> 6;                            // b*N + n
  int b = m >> 11;
  int n = m & (NN - 1);
  float inv = __fdiv_rn(gamma[c], __fsqrt_rn(__fadd_rn(var[c], BN_EPSF)));
  float shift = __fsub_rn(beta[c], __fmul_rn(mean[c], inv));
  const float* f = feats + (size_t)b * CC * NN + n;   // stride NN over c'
  float acc = 0.f;
#pragma unroll
  for (int cp = 0; cp < CC; ++cp) acc = fmaf(wlds[c * 65 + cp], f[(size_t)cp * NN], acc);
  G[t] = fmaf(inv, acc, shift);
}

// ---------------------------------------------------------------------------
// Kernel 2: exact KNN-SET. r16: survivors compacted as u64 (dist<<32 | j)
// keys; ONE u64 sort-64 orders them by (value asc, index asc) = exact
// reference tie-break, and the first 32 lanes store the answer directly.
// Deletes D extraction, the LE scans, the 32-iter emit loop, and the whole
// tie branch (~350 instr + 2 serial scan chains vs r15).
// T = A[31] of sorted lane-minima (theorem: at most 31 lane-minima < D).
// ntot>64 fallback: bit-descent + two-pass emit (proven r12-r15 path).
// ---------------------------------------------------------------------------
__global__ __launch_bounds__(256) void knn_kernel(const float4* __restrict__ P,
                                                  int* __restrict__ idx_out) {
  __shared__ u64 surv[4 * 64];              // wave-private survivor strips, 2KB
  const int lane = threadIdx.x & 63;
  const int wv = threadIdx.x >> 6;
  const int pid = blockIdx.x * 4 + wv;      // b*N + i
  const int b = pid >> 11;
  const int i = pid & (NN - 1);
  const float4* Pb = P + ((size_t)b << 11);
  float4 q = Pb[i];
  u64* sv = surv + wv * 64;
  const u64 lml = (1ull << lane) - 1ull;    // lanemask_lt

  u32 du[32];
  u32 m0 = 0xFFFFFFFFu;                     // lane minimum
#pragma unroll
  for (int c = 0; c < 32; ++c) {
    int j = (c << 6) | lane;
    float4 p = Pb[j];
    float dt = refdot3(q.x, q.y, q.z, p.x, p.y, p.z);
    u32 d = __float_as_uint(refdist(q.w, p.w, dt));
    du[c] = d;
    m0 = d < m0 ? d : m0;
  }

  // T = 32nd-smallest lane-minimum (>= D: at most 31 lane-minima < D)
  u32 Av = m0;
  WAVE_SORT64(Av);
  const u32 T = __shfl(Av, 31);

  // survivor count + exclusive scan -> per-lane write base
  u32 cls = 0;
#pragma unroll
  for (int c = 0; c < 32; ++c) cls += (du[c] <= T) ? 1u : 0u;
  u32 v2 = cls;
#pragma unroll
  for (int sft = 1; sft < 64; sft <<= 1) {
    u32 o = __shfl_up(v2, sft, 64);
    if (lane >= sft) v2 += o;
  }
  const u32 ntot = __shfl(v2, 63);
  int* op = idx_out + (size_t)pid * KK;

  if (ntot <= 64) {
    // compact survivor keys (per-lane sequential writes, no ballots)
    u32 pos = v2 - cls;
#pragma unroll
    for (int c = 0; c < 32; ++c) {
      if (du[c] <= T) {
        sv[pos] = ((u64)du[c] << 32) | (u64)(u32)((c << 6) | lane);
        ++pos;
      }
    }
    u64 x = (lane < (int)ntot) ? sv[lane] : ~0ull;
    WAVE_SORT64(x);
    if (lane < KK) op[lane] = (int)((u32)x & 0x7FFu);
  } else {
    // rare fallback: exact bit-descent for D, then two-pass emit with ties
    u32 ans = 0;
#pragma unroll 1
    for (int bbit = 30; bbit >= 0; --bbit) {
      u32 t2 = ans | (1u << bbit);
      u32 c2 = 0;
#pragma unroll
      for (int c = 0; c < 32; ++c) c2 += (du[c] < t2) ? 1u : 0u;
#pragma unroll
      for (int sft = 1; sft < 64; sft <<= 1) c2 += __shfl_xor(c2, sft);
      if (c2 < KK) ans = t2;
    }
    const u32 D = ans;
    u32 cntL = 0;
#pragma unroll
    for (int c = 0; c < 32; ++c) cntL += (du[c] < D) ? 1u : 0u;
    u32 vL = cntL;
#pragma unroll
    for (int sft = 1; sft < 64; sft <<= 1) {
      u32 o = __shfl_up(vL, sft, 64);
      if (lane >= sft) vL += o;
    }
    const u32 r = KK - __shfl(vL, 63);
    u32 pos = vL - cntL;
#pragma unroll
    for (int c = 0; c < 32; ++c) {
      if (du[c] < D) { op[pos] = (c << 6) | lane; ++pos; }
    }
    u32 emit = r;
    u32 wpos = KK - r;
#pragma unroll
    for (int c = 0; c < 32; ++c) {
      if (emit != 0) {
        u64 mk = __ballot(du[c] == D);
        u32 pc = (u32)__popcll(mk);
        u32 rk = (u32)__popcll(mk & lml);
        if ((du[c] == D) && rk < emit) op[wpos + rk] = (c << 6) | lane;
        u32 take = pc < emit ? pc : emit;
        wpos += take;
        emit -= take;
      }
    }
  }
}

// ---------------------------------------------------------------------------
// Kernel 3: fused density + aggregation, two points per wave (r15 structure).
// r16: agg broadcast via LDS (1 ds_read_b128 + 1 ds_read_b32 per k, wave-
// uniform = conflict-free) instead of 5 ds_bpermute shfls (~190 DS ops/wave
// saved). Density math byte-identical to the proven kernel.
// ---------------------------------------------------------------------------
__global__ __launch_bounds__(256) void dagg_kernel(
    const float4* __restrict__ P, const float* __restrict__ conv_w,
    const float* __restrict__ gamma, const float* __restrict__ var,
    const float* __restrict__ G, const int* __restrict__ idxb,
    float* __restrict__ out) {
  __shared__ float4 ldsRW[4][64];           // (rx,ry,rz,wk) per lane
  __shared__ int ldsJ[4][64];               // pre-scaled j*64 row offsets
  const int lane = threadIdx.x & 63;
  const int wv = threadIdx.x >> 6;
  const int half = lane >> 5;
  const int k = lane & 31;
  const int pid_pair = blockIdx.x * 8 + wv * 2;   // even; never crosses batch
  const int pid = pid_pair + half;                 // this half's point
  const int b = pid >> 11;
  const float4* Pb = P + ((size_t)b << 11);

  const int i = pid & (NN - 1);
  float4 q = Pb[i];                       // broadcast within each half
  int jk = idxb[(size_t)pid * KK + k];    // neighbor index (lane half*32+k)
  float4 nb = Pb[jk];                     // neighbor coords + refsq3 norm

  // rel for agg: (n - c)/R, ref rounding
  float rx = __fdiv_rn(__fsub_rn(nb.x, q.x), RADIUSF);
  float ry = __fdiv_rn(__fsub_rn(nb.y, q.y), RADIUSF);
  float rz = __fdiv_rn(__fsub_rn(nb.z, q.z), RADIUSF);

  // --- density phase (per half): 16th smallest of 32 neighbor-distances ---
  u32 d2b[32];
#pragma unroll
  for (int t = 0; t < 32; ++t) {
    float ox = __shfl(nb.x, t, 32);
    float oy = __shfl(nb.y, t, 32);
    float oz = __shfl(nb.z, t, 32);
    float so = __shfl(nb.w, t, 32);
    float dt = refdot3(nb.x, nb.y, nb.z, ox, oy, oz);
    float d2 = __fsub_rn(__fadd_rn(nb.w, so), __fmul_rn(2.0f, dt));
    d2 = fmaxf(d2, 0.0f);
    d2b[t] = (t == k) ? 0x7F800000u : __float_as_uint(d2);  // eye = +inf
  }
  // Batcher sort 32 u32 ascending (d2 bits monotone; 16th VALUE commutes
  // with the monotone sqrt)
#pragma unroll
  for (int p = 1; p < 32; p <<= 1) {
#pragma unroll
    for (int kk = p; kk >= 1; kk >>= 1) {
#pragma unroll
      for (int jj = (kk & (p - 1)); jj + kk < 32; jj += 2 * kk) {
#pragma unroll
        for (int t = 0; t < kk; ++t) {
          if ((t + jj) / (2 * p) == (t + jj + kk) / (2 * p)) {
            u32 a = d2b[t + jj], b2 = d2b[t + jj + kk];
            d2b[t + jj] = a < b2 ? a : b2;
            d2b[t + jj + kk] = a < b2 ? b2 : a;
          }
        }
      }
    }
  }
  float kd2 = __uint_as_float(d2b[DK - 1]);
  float kth = kd2 > 0.f ? __fsqrt_rn(kd2) : 0.f;
  float r1 = fmaxf(kth, EPSF);
  float raw = __fmul_rn(__fmul_rn(r1, r1), r1);
  float s = raw;
#pragma unroll
  for (int t = 1; t < 32; t <<= 1) s += __shfl_xor(s, t, 32);
  float wk = raw / fmaxf(s, EPSF);        // w_k in lane half*32+k

  // stage per-k data for the broadcast agg phase (same-wave DS: in-order)
  ldsRW[wv][lane] = make_float4(rx, ry, rz, wk);
  ldsJ[wv][lane] = jk * 64;

  // --- agg phase: lane = channel; two points sequentially ---
  float inv = __fdiv_rn(gamma[lane], __fsqrt_rn(__fadd_rn(var[lane], BN_EPSF)));
  float w0 = conv_w[lane * (CC + 3) + 0] * inv;
  float w1 = conv_w[lane * (CC + 3) + 1] * inv;
  float w2 = conv_w[lane * (CC + 3) + 2] * inv;
  const float* Gb = G + ((size_t)b * NN) * 64 + lane;

#pragma unroll
  for (int h2 = 0; h2 < 2; ++h2) {
    const int pid2 = pid_pair + h2;
    const int i2 = pid2 & (NN - 1);
    float acc = 0.f;
#pragma unroll
    for (int kk2 = 0; kk2 < KK; ++kk2) {
      float4 rw = ldsRW[wv][h2 * 32 + kk2];   // broadcast read
      int joff = ldsJ[wv][h2 * 32 + kk2];
      float g = Gb[joff];
      float y = fmaf(w2, rw.z, fmaf(w1, rw.y, fmaf(w0, rw.x, g)));
      y = fmaxf(y, 0.f);
      acc = fmaf(rw.w, y, acc);
    }
    out[((size_t)(b * 64 + lane)) * NN + i2] = acc;
  }
}

// ---------------------------------------------------------------------------
extern "C" void kernel_launch(void* const* d_in, const int* in_sizes, int n_in,
                              void* d_out, int out_size, void* d_ws, size_t ws_size,
                              hipStream_t stream) {
  const float* coords = (const float*)d_in[0];
  const float* feats  = (const float*)d_in[1];
  const float* conv_w = (const float*)d_in[2];
  const float* gamma  = (const float*)d_in[3];
  const float* beta   = (const float*)d_in[4];
  const float* mean   = (const float*)d_in[5];
  const float* var    = (const float*)d_in[6];
  float* out = (float*)d_out;

  int*   idxb = (int*)d_ws;                                          // 2 MB
  float4* P   = (float4*)((char*)d_ws + (size_t)2 * 1024 * 1024);    // 256 KB
  float* G    = (float*)((char*)d_ws + (size_t)4 * 1024 * 1024);     // 4 MB

  const int NPTS = BB * NN;   // 16384

  pack_kernel<<<NPTS / 256, 256, 0, stream>>>(coords, P);
  knn_kernel<<<NPTS / 4, 256, 0, stream>>>(P, idxb);
  gfeat_kernel<<<(NPTS * CC) / 256, 256, 0, stream>>>(feats, conv_w, gamma, beta,
                                                      mean, var, G);
  dagg_kernel<<<NPTS / 8, 256, 0, stream>>>(P, conv_w, gamma, var, G, idxb, out);
}